// Round 3
// baseline (207.402 us; speedup 1.0000x reference)
//
#include <hip/hip_runtime.h>
#include <stdint.h>

// Problem constants (from reference)
#define B_   128
#define C_   3
#define H_   256
#define W_   256
#define CH_  64          // cutout height = int(256*0.25)
#define CW_  64          // cutout width
#define HW_  (H_ * W_)   // 65536 elements per plane
#define NPLANES (B_ * C_)
#define PROB_ 0.9f
// factor = 1 - K + 2*K*u = 0.8 + 0.4*u  for K = 0.2 (BRI/CON/SAT)

// ---------- bf16 helpers (raw ushort bit handling, fp32 math) ----------
__device__ __forceinline__ float bf_lo(uint32_t u) {
    union { uint32_t u; float f; } c; c.u = u << 16; return c.f;
}
__device__ __forceinline__ float bf_hi(uint32_t u) {
    union { uint32_t u; float f; } c; c.u = u & 0xFFFF0000u; return c.f;
}
__device__ __forceinline__ float bf_val(uint16_t v) {
    union { uint32_t u; float f; } c; c.u = ((uint32_t)v) << 16; return c.f;
}
__device__ __forceinline__ uint16_t f2bf(float f) {
    // round-to-nearest-even; values here are finite
    union { float f; uint32_t u; } c; c.f = f;
    uint32_t u = c.u;
    return (uint16_t)((u + 0x7FFFu + ((u >> 16) & 1u)) >> 16);
}
__device__ __forceinline__ void unpack8(uint4 v, float e[8]) {
    e[0] = bf_lo(v.x); e[1] = bf_hi(v.x);
    e[2] = bf_lo(v.y); e[3] = bf_hi(v.y);
    e[4] = bf_lo(v.z); e[5] = bf_hi(v.z);
    e[6] = bf_lo(v.w); e[7] = bf_hi(v.w);
}

// Scalar decode honoring detected layout: bf16[b] vs fp32[b]
__device__ __forceinline__ float scal(const void* p, int b, int is_bf16) {
    if (is_bf16) return bf_val(((const uint16_t*)p)[b]);
    return ((const float*)p)[b];
}

// Wave-0 dtype sniffer: view first 256 B as 128 bf16. bf16 uniform[0,1) data
// -> all in [0,1). fp32 data -> low-half words are random mantissa bits,
// P(all 64 in range) ~ 0.25^64 ~ 1e-39. Call with threadIdx.x < 64 only.
__device__ __forceinline__ bool sniff_bf16_01(const uint16_t* u, int lane) {
    bool ok = true;
    #pragma unroll
    for (int k = 0; k < 2; ++k) {
        float v = bf_val(u[lane + 64 * k]);
        ok = ok && (v >= 0.0f) && (v < 1.0f);   // NaN -> false
    }
    unsigned long long m = __ballot(ok);
    return m == ~0ull;
}

// ---------- Pass 1: per-(b,c) raw spatial mean + dtype sniffers ----------
// 384 blocks, one per plane, 512 threads.
__global__ __launch_bounds__(512) void plane_mean_kernel(
    const void* __restrict__ img, const void* __restrict__ apply_u,
    float* __restrict__ means, int* __restrict__ flags)
{
    __shared__ int s_imgbf;
    if (threadIdx.x < 64) {
        const bool ib = sniff_bf16_01((const uint16_t*)img, threadIdx.x);
        bool sb = false;
        if (blockIdx.x == 0) sb = sniff_bf16_01((const uint16_t*)apply_u, threadIdx.x);
        if (threadIdx.x == 0) {
            s_imgbf = ib ? 1 : 0;
            if (blockIdx.x == 0) { flags[0] = ib ? 1 : 0; flags[1] = sb ? 1 : 0; }
        }
    }
    __syncthreads();
    const int imgbf = s_imgbf;
    const int plane = blockIdx.x;

    float s = 0.0f;
    if (imgbf) {
        const uint4* p = (const uint4*)((const uint16_t*)img + (size_t)plane * HW_);
        for (int i = threadIdx.x; i < HW_ / 8; i += 512) {
            float e[8]; unpack8(p[i], e);
            s += ((e[0] + e[1]) + (e[2] + e[3])) + ((e[4] + e[5]) + (e[6] + e[7]));
        }
    } else {
        const float4* p = (const float4*)((const float*)img + (size_t)plane * HW_);
        for (int i = threadIdx.x; i < HW_ / 4; i += 512) {
            float4 v = p[i];
            s += (v.x + v.y) + (v.z + v.w);
        }
    }

    // wave (64) reduction
    #pragma unroll
    for (int off = 32; off > 0; off >>= 1) s += __shfl_down(s, off, 64);

    __shared__ float wsum[8];
    const int wave = threadIdx.x >> 6;
    if ((threadIdx.x & 63) == 0) wsum[wave] = s;
    __syncthreads();
    if (threadIdx.x == 0) {
        float t = 0.0f;
        #pragma unroll
        for (int i = 0; i < 8; ++i) t += wsum[i];
        means[plane] = t * (1.0f / (float)HW_);
    }
}

// ---------- Pass 2: fused flip/brightness/contrast/saturation/cutout/select ----------
// One thread = 8 consecutive pixels across all 3 channels. 32 blocks of 256
// threads per batch item -> b is block-uniform (no divergence on apply/flip).
__global__ __launch_bounds__(256) void augment_kernel(
    const void* __restrict__ img,
    const void* __restrict__ apply_u,
    const void* __restrict__ flip_u,
    const void* __restrict__ bri_u,
    const void* __restrict__ con_u,
    const void* __restrict__ sat_u,
    const int*  __restrict__ top_idx,
    const int*  __restrict__ left_idx,
    const float* __restrict__ means,
    const int*  __restrict__ flags,
    void*       __restrict__ out)
{
    const int imgbf = __builtin_amdgcn_readfirstlane(flags[0]);
    const int scbf  = __builtin_amdgcn_readfirstlane(flags[1]);

    const int b   = blockIdx.x >> 5;                          // 32 blocks / batch
    const int rem = ((blockIdx.x & 31) << 8) + threadIdx.x;   // vec idx within batch [0,8192)
    const int h   = rem >> 5;                                 // 32 vecs per row
    const int w0  = (rem & 31) << 3;                          // pixel col base

    const size_t base = (size_t)b * (C_ * HW_) + (size_t)h * W_ + (size_t)w0;

    const bool apply = scal(apply_u, b, scbf) < PROB_;
    if (!apply) {
        // bit-exact passthrough of the original image
        if (imgbf) {
            const uint16_t* ip = (const uint16_t*)img;
            uint16_t*       op = (uint16_t*)out;
            #pragma unroll
            for (int c = 0; c < 3; ++c)
                *(uint4*)(op + base + (size_t)c * HW_) =
                    *(const uint4*)(ip + base + (size_t)c * HW_);
        } else {
            const float* ip = (const float*)img;
            float*       op = (float*)out;
            #pragma unroll
            for (int c = 0; c < 3; ++c) {
                *(float4*)(op + base + (size_t)c * HW_)     = *(const float4*)(ip + base + (size_t)c * HW_);
                *(float4*)(op + base + (size_t)c * HW_ + 4) = *(const float4*)(ip + base + (size_t)c * HW_ + 4);
            }
        }
        return;
    }

    const bool  flip = scal(flip_u, b, scbf) < 0.5f;
    const float fb   = 0.8f + 0.4f * scal(bri_u, b, scbf);
    const float fc   = 0.8f + 0.4f * scal(con_u, b, scbf);
    const float fs   = 0.8f + 0.4f * scal(sat_u, b, scbf);
    const int   t    = top_idx[b];
    const int   l    = left_idx[b];

    // flipped source: output cols [w0, w0+7] <- source cols [255-w0-7 .. 255-w0]
    const int sw = flip ? (W_ - 8 - w0) : w0;
    const size_t sbase = (size_t)b * (C_ * HW_) + (size_t)h * W_ + (size_t)sw;

    float x[3][8];
    #pragma unroll
    for (int c = 0; c < 3; ++c) {
        float e[8];
        if (imgbf) {
            uint4 v = *(const uint4*)((const uint16_t*)img + sbase + (size_t)c * HW_);
            unpack8(v, e);
        } else {
            const float* ip = (const float*)img + sbase + (size_t)c * HW_;
            float4 v0 = *(const float4*)(ip);
            float4 v1 = *(const float4*)(ip + 4);
            e[0] = v0.x; e[1] = v0.y; e[2] = v0.z; e[3] = v0.w;
            e[4] = v1.x; e[5] = v1.y; e[6] = v1.z; e[7] = v1.w;
        }
        // mean after brightness = fb * raw_mean (flip doesn't change the mean)
        const float m = fb * means[b * 3 + c];
        #pragma unroll
        for (int j = 0; j < 8; ++j) {
            const float src = flip ? e[7 - j] : e[j];
            x[c][j] = (src * fb - m) * fc + m;   // brightness + contrast
        }
    }

    // saturation (per-pixel channel mean) + cutout
    const bool row_in = (h >= t) && (h < t + CH_);
    #pragma unroll
    for (int j = 0; j < 8; ++j) {
        const float gray = (x[0][j] + x[1][j] + x[2][j]) * (1.0f / 3.0f);
        const int   w    = w0 + j;
        const bool inside = row_in && (w >= l) && (w < l + CW_);
        #pragma unroll
        for (int c = 0; c < 3; ++c) {
            const float y = (x[c][j] - gray) * fs + gray;
            x[c][j] = inside ? 0.0f : y;
        }
    }

    // pack + store (output dtype follows images dtype)
    if (imgbf) {
        uint16_t* op = (uint16_t*)out;
        #pragma unroll
        for (int c = 0; c < 3; ++c) {
            uint4 ov;
            ov.x = (uint32_t)f2bf(x[c][0]) | ((uint32_t)f2bf(x[c][1]) << 16);
            ov.y = (uint32_t)f2bf(x[c][2]) | ((uint32_t)f2bf(x[c][3]) << 16);
            ov.z = (uint32_t)f2bf(x[c][4]) | ((uint32_t)f2bf(x[c][5]) << 16);
            ov.w = (uint32_t)f2bf(x[c][6]) | ((uint32_t)f2bf(x[c][7]) << 16);
            *(uint4*)(op + base + (size_t)c * HW_) = ov;
        }
    } else {
        float* op = (float*)out;
        #pragma unroll
        for (int c = 0; c < 3; ++c) {
            float4 v0, v1;
            v0.x = x[c][0]; v0.y = x[c][1]; v0.z = x[c][2]; v0.w = x[c][3];
            v1.x = x[c][4]; v1.y = x[c][5]; v1.z = x[c][6]; v1.w = x[c][7];
            *(float4*)(op + base + (size_t)c * HW_)     = v0;
            *(float4*)(op + base + (size_t)c * HW_ + 4) = v1;
        }
    }
}

extern "C" void kernel_launch(void* const* d_in, const int* in_sizes, int n_in,
                              void* d_out, int out_size, void* d_ws, size_t ws_size,
                              hipStream_t stream) {
    const void* img     = d_in[0];
    const void* apply_u = d_in[1];
    const void* flip_u  = d_in[2];
    const void* bri_u   = d_in[3];
    const void* con_u   = d_in[4];
    const void* sat_u   = d_in[5];
    const int*  top_i   = (const int*)d_in[6];
    const int*  left_i  = (const int*)d_in[7];
    float*      means   = (float*)d_ws;                          // 384 floats
    int*        flags   = (int*)((char*)d_ws + NPLANES * sizeof(float)); // 2 ints

    plane_mean_kernel<<<NPLANES, 512, 0, stream>>>(img, apply_u, means, flags);

    const int total_vecs = B_ * HW_ / 8;                         // 1,048,576
    augment_kernel<<<total_vecs / 256, 256, 0, stream>>>(
        img, apply_u, flip_u, bri_u, con_u, sat_u, top_i, left_i, means, flags, d_out);
}